// Round 4
// baseline (458.322 us; speedup 1.0000x reference)
//
#include <hip/hip_runtime.h>

#define TSTEPS 48
#define OUT_STEPS 24
#define L2E 1.44269504088896340736f
#define ECLAMP 30.0f

typedef short bf16x8 __attribute__((ext_vector_type(8)));
typedef float f32x16 __attribute__((ext_vector_type(16)));
typedef unsigned int u32x4 __attribute__((ext_vector_type(4)));

// RNE bf16 hi + truncated-residual lo (weights; off hot path).
__device__ __forceinline__ void bf_split_rne(float f, short& hi, short& lo) {
    unsigned u = __builtin_bit_cast(unsigned, f);
    unsigned r = u + 0x7FFFu + ((u >> 16) & 1u);
    unsigned short hb = (unsigned short)(r >> 16);
    float hif = __builtin_bit_cast(float, (unsigned)hb << 16);
    float lof = f - hif;
    unsigned short lb = (unsigned short)(__builtin_bit_cast(unsigned, lof) >> 16);
    hi = (short)hb; lo = (short)lb;
}

// Truncation split packed into one dword: low16 = hi-bf16, high16 = lo-bf16.
__device__ __forceinline__ unsigned split_pack(float f) {
    unsigned u = __builtin_bit_cast(unsigned, f);
    float hif = __builtin_bit_cast(float, u & 0xFFFF0000u);
    float lof = f - hif;
    unsigned lo = __builtin_bit_cast(unsigned, lof);
    return (u >> 16) | (lo & 0xFFFF0000u);
}

// Gate pre-scale for exp2: i,f,o -> -log2e; g (gate 2) -> -2*log2e.
__device__ __forceinline__ float gate_scale(int g) {
    return (g == 2) ? (-2.0f * L2E) : (-L2E);
}

// U-frag LDS slot: ((cell*4+g)*2+c)*2+hl, address (slot*64+lane)*16B.
// Lane-contiguous b128 reads/writes — the m97 fast path, conflict-free.
__device__ __forceinline__ int uslot(int cell, int g, int c, int hl) {
    return ((cell * 4 + g) * 2 + c) * 2 + hl;
}

// Stage ONE cell's A4 frags into LDS (4 KB). Called by wave 0 only; restaged
// at the warmup->decode transition (off the hot path, behind barriers).
__device__ __forceinline__ void stage_a4(short* __restrict__ a4lds,
                                         const float* __restrict__ Wks,
                                         const float* __restrict__ bvs,
                                         int m, int H, int lane) {
#pragma unroll
    for (int g = 0; g < 4; ++g) {
        const float s = gate_scale(g);
        short whi, wlo, bhi, blo;
        bf_split_rne(Wks[g * 32 + m] * s, whi, wlo);
        bf_split_rne(bvs[g * 32 + m] * s, bhi, blo);
        // A4: [wk_hi, wk_hi, wk_lo, b_hi, b_lo, 0,0,0] on H==0 lanes, else 0.
        bf16x8 a = {whi, whi, wlo, bhi, blo, 0, 0, 0};
        u32x4 z4 = {0u, 0u, 0u, 0u};
        if (H != 0) a = __builtin_bit_cast(bf16x8, z4);
        *(bf16x8*)(a4lds + (g * 64 + lane) * 8) = a;
    }
}

// One LSTM step for 32 batch rows. h enters/exits as two K-half B-frags held
// as u32x4 (packed bf16 pairs, built with v_perm_b32). U-frags + A4 read from
// LDS each step (shared by all 4 waves; keeps arch VGPRs <= 64 so
// launch_bounds(256,4) is spill-free alongside acc's 64 AGPRs).
//
// TRANS-PIPE DIET (R4): the trans unit is the saturated resource (VALUBusy
// invariant ~69% across occupancy 12->16 waves/CU and stagger — R0..R3).
// Reciprocals batched across independent rows: c'-divisions 4-way (dens are
// all >=1 and <= ~3e8 -> product <= ~5e33, overflow-safe; 1 rcp + 9 mul
// replaces 4 rcp), h-divisions pairwise (dens <= ~1e12 -> pair product safe).
// Trans count 7 -> 5.75 per cell; extra muls ride the idle VALU pipe.
// rcp-composition error ~5e-7 rel — far below the bf16 4.88e-4 floor.
template <bool NEED_P>
__device__ __forceinline__ float lstm_step32(unsigned xpack,
    const short* __restrict__ ufbase,          // &uflds[cell-base]
    const short* __restrict__ a4cell,          // &a4lds[0]
    u32x4& B0h, u32x4& B0l, u32x4& B1h, u32x4& B1l,
    float* cs, const float* __restrict__ wdp,  // &wdlds[H][0] (broadcast)
    int lane, int H) {
    // B4 on H==0 lanes: [x_hi, x_lo, x_hi, 1, 1, 0,0,0].
    unsigned w0 = xpack;
    unsigned w1 = (xpack & 0xFFFFu) | 0x3F800000u;
    unsigned w2 = 0x00003F80u;
    if (H != 0) { w0 = 0u; w1 = 0u; w2 = 0u; }
    u32x4 b4u = {w0, w1, w2, 0u};
    const bf16x8 B4 = __builtin_bit_cast(bf16x8, b4u);
    const bf16x8 b0h = __builtin_bit_cast(bf16x8, B0h);
    const bf16x8 b0l = __builtin_bit_cast(bf16x8, B0l);
    const bf16x8 b1h = __builtin_bit_cast(bf16x8, B1h);
    const bf16x8 b1l = __builtin_bit_cast(bf16x8, B1l);
    const f32x16 zero16 = {0,0,0,0,0,0,0,0,0,0,0,0,0,0,0,0};

    f32x16 acc[4];
#pragma unroll
    for (int g = 0; g < 4; ++g) {
        const bf16x8 A4g = *(const bf16x8*)(a4cell + (g * 64 + lane) * 8);
        const bf16x8 Ah0 = *(const bf16x8*)(ufbase + (uslot(0, g, 0, 0) * 64 + lane) * 8);
        const bf16x8 Al0 = *(const bf16x8*)(ufbase + (uslot(0, g, 0, 1) * 64 + lane) * 8);
        const bf16x8 Ah1 = *(const bf16x8*)(ufbase + (uslot(0, g, 1, 0) * 64 + lane) * 8);
        const bf16x8 Al1 = *(const bf16x8*)(ufbase + (uslot(0, g, 1, 1) * 64 + lane) * 8);
        f32x16 a = __builtin_amdgcn_mfma_f32_32x32x16_bf16(A4g, B4, zero16, 0, 0, 0);
        a = __builtin_amdgcn_mfma_f32_32x32x16_bf16(Al0, b0h, a, 0, 0, 0);
        a = __builtin_amdgcn_mfma_f32_32x32x16_bf16(Ah0, b0l, a, 0, 0, 0);
        a = __builtin_amdgcn_mfma_f32_32x32x16_bf16(Ah0, b0h, a, 0, 0, 0);
        a = __builtin_amdgcn_mfma_f32_32x32x16_bf16(Al1, b1h, a, 0, 0, 0);
        a = __builtin_amdgcn_mfma_f32_32x32x16_bf16(Ah1, b1l, a, 0, 0, 0);
        a = __builtin_amdgcn_mfma_f32_32x32x16_bf16(Ah1, b1h, a, 0, 0, 0);
        acc[g] = a;
    }

    float pp = 0.0f;
#pragma unroll
    for (int qg = 0; qg < 4; ++qg) {   // groups of 4 independent rows
        const int r0 = qg * 4;
        float numv[4], denv[4], dov[4];
#pragma unroll
        for (int k = 0; k < 4; ++k) {
            const int r = r0 + k;
            float ei = __builtin_amdgcn_exp2f(acc[0][r]);
            float ef = __builtin_amdgcn_exp2f(acc[1][r]);
            float eg = __builtin_amdgcn_exp2f(__builtin_fminf(acc[2][r], ECLAMP));
            float eo = __builtin_amdgcn_exp2f(acc[3][r]);
            float di = 1.0f + ei, df = 1.0f + ef, dg = 1.0f + eg;
            dov[k] = 1.0f + eo;
            float ngs = __builtin_fmaf(eg, 2.0f * L2E, -2.0f * L2E);  // -2L2E*(1-eg)
            float t1 = di * dg;
            float t2 = cs[r] * t1;
            numv[k] = __builtin_fmaf(ngs, df, t2);
            denv[k] = df * t1;        // in [1, ~3e8] — 4-product is f32-safe
        }
        // ONE rcp for all four c'-divisions (prefix/suffix reconstruction).
        float p01 = denv[0] * denv[1], p23 = denv[2] * denv[3];
        float tq = __builtin_amdgcn_rcpf(p01 * p23);
        float q01 = tq * p23, q23 = tq * p01;
        float inv0 = q01 * denv[1], inv1 = q01 * denv[0];
        float inv2 = q23 * denv[3], inv3 = q23 * denv[2];
        float ecv[4];
        {
            float cn0 = numv[0] * inv0; cs[r0 + 0] = cn0;
            float cn1 = numv[1] * inv1; cs[r0 + 1] = cn1;
            float cn2 = numv[2] * inv2; cs[r0 + 2] = cn2;
            float cn3 = numv[3] * inv3; cs[r0 + 3] = cn3;
            ecv[0] = __builtin_amdgcn_exp2f(__builtin_fminf(cn0, ECLAMP));
            ecv[1] = __builtin_amdgcn_exp2f(__builtin_fminf(cn1, ECLAMP));
            ecv[2] = __builtin_amdgcn_exp2f(__builtin_fminf(cn2, ECLAMP));
            ecv[3] = __builtin_amdgcn_exp2f(__builtin_fminf(cn3, ECLAMP));
        }
        // h-divisions batched in pairs (dens can reach ~1e12; pairs stay safe).
        float hv[4];
#pragma unroll
        for (int k = 0; k < 4; k += 2) {
            float d0 = dov[k] * (1.0f + ecv[k]);
            float d1 = dov[k + 1] * (1.0f + ecv[k + 1]);
            float tp = __builtin_amdgcn_rcpf(d0 * d1);
            hv[k]     = (1.0f - ecv[k])     * (tp * d1);   // o*tanh(c)
            hv[k + 1] = (1.0f - ecv[k + 1]) * (tp * d0);
        }
        if constexpr (NEED_P) {
#pragma unroll
            for (int k = 0; k < 4; ++k)
                pp = __builtin_fmaf(hv[k], wdp[r0 + k], pp);  // LDS broadcast
        }
        // pack pairs into B-frags (identical bit pattern to R3's perm path).
#pragma unroll
        for (int k = 0; k < 4; k += 2) {
            unsigned ue = __builtin_bit_cast(unsigned, hv[k]);
            unsigned uo = __builtin_bit_cast(unsigned, hv[k + 1]);
            float hife = __builtin_bit_cast(float, ue & 0xFFFF0000u);
            float hifo = __builtin_bit_cast(float, uo & 0xFFFF0000u);
            unsigned le  = __builtin_bit_cast(unsigned, hv[k]     - hife);
            unsigned lo_ = __builtin_bit_cast(unsigned, hv[k + 1] - hifo);
            unsigned hw = __builtin_amdgcn_perm(uo, ue, 0x07060302u);
            unsigned lw = __builtin_amdgcn_perm(lo_, le, 0x07060302u);
            const int qi = (r0 + k) >> 1;  // compile-time after unroll
            if (qi < 4) { B0h[qi] = hw; B0l[qi] = lw; }
            else        { B1h[qi - 4] = hw; B1l[qi - 4] = lw; }
        }
    }
    return pp;
}

// (256,4): LDS 37 KB, arch ~64 + 64 acc VGPR -> 16 waves/CU, whole grid
// co-resident. Stagger removed (R3: pure +7 us cost, VALUBusy unmoved —
// the bottleneck is the trans pipe, not wave phasing).
__global__ __launch_bounds__(256, 4) void lstm_feedback_mfma17(
    const float* __restrict__ inputs,  // [B, 48]
    const float* __restrict__ Wk_w, const float* __restrict__ Uk_w, const float* __restrict__ b_w,
    const float* __restrict__ Wk_d, const float* __restrict__ Uk_d, const float* __restrict__ b_d,
    const float* __restrict__ Wd, const float* __restrict__ bd,
    float* __restrict__ out,           // [B, 24]
    int B) {
    const int tid = threadIdx.x;       // 4 waves x 32 batch = 128 batch/block
    const int w = tid >> 6;
    const int lane = tid & 63;
    const int m = lane & 31;           // batch column within wave / out-unit row
    const int H = lane >> 5;
    const int mblk = blockIdx.x * 128;
    const long row = (long)(mblk + w * 32 + m);

    __shared__ __align__(16) short uflds[32 * 64 * 8];  // 32 KB: both cells' U-frags
    __shared__ __align__(16) short a4lds[4 * 64 * 8];   // 4 KB: ONE cell's A4
    __shared__ float wdlds[2][16];                      // Wd in D-reg order

    // Waves 0/1 stage cell 0/1: U-frags (pre-scaled, permuted, hi/lo split).
    if (w < 2) {
        const float* Uks = w ? Uk_d : Uk_w;
#pragma unroll
        for (int g = 0; g < 4; ++g) {
            const float s = gate_scale(g);
#pragma unroll
            for (int c = 0; c < 2; ++c) {
                bf16x8 ah, al;
#pragma unroll
                for (int j = 0; j < 8; ++j) {
                    const int uin = 16 * c + 4 * H + (j & 3) + 8 * (j >> 2);
                    float wt = Uks[uin * 128 + g * 32 + m] * s;
                    short hb, lb; bf_split_rne(wt, hb, lb);
                    ah[j] = hb; al[j] = lb;
                }
                *(bf16x8*)(uflds + (uslot(w, g, c, 0) * 64 + lane) * 8) = ah;
                *(bf16x8*)(uflds + (uslot(w, g, c, 1) * 64 + lane) * 8) = al;
            }
        }
    }
    // Warmup cell's A4 (wave 0 covers all 64 lanes x 4 gates).
    if (w == 0) stage_a4(a4lds, Wk_w, b_w, m, H, lane);
    // Wd in D-layout order: unit of D reg r is (r&3) + 8*(r>>2) + 4H.
    if (tid < 32) {
        const int r = tid & 15, Hh = tid >> 4;
        wdlds[Hh][r] = Wd[(r & 3) + 8 * (r >> 2) + 4 * Hh];
    }

    u32x4 z4 = {0u, 0u, 0u, 0u};
    u32x4 B0h = z4, B0l = z4, B1h = z4, B1l = z4;
    float cs[16];
#pragma unroll
    for (int r = 0; r < 16; ++r) cs[r] = 0.0f;

    __syncthreads();  // uflds + a4lds + wdlds visible

    const short* __restrict__ uf_w = uflds;
    const short* __restrict__ uf_d = uflds + 16 * 64 * 8;
    const float* __restrict__ wdp = &wdlds[H][0];

    // ---- warmup: per-lane x from global (L2-resident), one-step prefetch ----
    float xc = inputs[row * TSTEPS + 0];
    for (int t = 0; t < TSTEPS - 1; ++t) {
        float xn = inputs[row * TSTEPS + t + 1];  // issued before the step body
        asm volatile("" ::: "memory");  // keep LDS frag reads in-loop (anti-LICM)
        lstm_step32<false>(split_pack(xc), uf_w, a4lds,
                           B0h, B0l, B1h, B1l, cs, wdp, lane, H);
        xc = xn;
    }

    const float bdv = bd[0];

    // ---- last warmup step with pred fold; single-shuffle reduce ----
    asm volatile("" ::: "memory");
    float p = lstm_step32<true>(split_pack(xc), uf_w, a4lds,
                                B0h, B0l, B1h, B1l, cs, wdp, lane, H);
    p += __shfl_xor(p, 32);
    p += bdv;                          // both H lanes of batch m hold pred(batch m)
    if (H == 0) out[row * OUT_STEPS + 0] = p;

    // ---- transition: restage A4 for the decode cell (once, off hot path) ----
    __syncthreads();                   // all waves done reading warmup A4
    if (w == 0) stage_a4(a4lds, Wk_d, b_d, m, H, lane);
    __syncthreads();                   // decode A4 visible

    // ---- decode: U pointer swap; A4 already swapped in LDS ----
    for (int s = 1; s < OUT_STEPS; ++s) {
        asm volatile("" ::: "memory");
        p = lstm_step32<true>(split_pack(p), uf_d, a4lds,
                              B0h, B0l, B1h, B1l, cs, wdp, lane, H);
        p += __shfl_xor(p, 32);
        p += bdv;
        if (H == 0) out[row * OUT_STEPS + s] = p;
    }
}

extern "C" void kernel_launch(void* const* d_in, const int* in_sizes, int n_in,
                              void* d_out, int out_size, void* d_ws, size_t ws_size,
                              hipStream_t stream) {
    const float* inputs = (const float*)d_in[0];
    const float* Wk_w   = (const float*)d_in[1];
    const float* Uk_w   = (const float*)d_in[2];
    const float* b_w    = (const float*)d_in[3];
    const float* Wk_d   = (const float*)d_in[4];
    const float* Uk_d   = (const float*)d_in[5];
    const float* b_d    = (const float*)d_in[6];
    const float* Wd     = (const float*)d_in[7];
    const float* bd     = (const float*)d_in[8];
    float* out = (float*)d_out;

    const int B = in_sizes[0] / TSTEPS;
    const int grid = (B + 127) / 128;  // 128 batch rows per 256-thread block
    lstm_feedback_mfma17<<<grid, 256, 0, stream>>>(
        inputs, Wk_w, Uk_w, b_w, Wk_d, Uk_d, b_d, Wd, bd, out, B);
}

// Round 6
// 390.524 us; speedup vs baseline: 1.1736x; 1.1736x over previous
//
#include <hip/hip_runtime.h>

#define TSTEPS 48
#define OUT_STEPS 24
#define L2E 1.44269504088896340736f
#define ECLAMP 30.0f

typedef short bf16x8 __attribute__((ext_vector_type(8)));
typedef float f32x16 __attribute__((ext_vector_type(16)));
typedef unsigned int u32x4 __attribute__((ext_vector_type(4)));

// RNE bf16 hi + truncated-residual lo (weights; off hot path).
__device__ __forceinline__ void bf_split_rne(float f, short& hi, short& lo) {
    unsigned u = __builtin_bit_cast(unsigned, f);
    unsigned r = u + 0x7FFFu + ((u >> 16) & 1u);
    unsigned short hb = (unsigned short)(r >> 16);
    float hif = __builtin_bit_cast(float, (unsigned)hb << 16);
    float lof = f - hif;
    unsigned short lb = (unsigned short)(__builtin_bit_cast(unsigned, lof) >> 16);
    hi = (short)hb; lo = (short)lb;
}

// Truncation split packed into one dword: low16 = hi-bf16, high16 = lo-bf16.
__device__ __forceinline__ unsigned split_pack(float f) {
    unsigned u = __builtin_bit_cast(unsigned, f);
    float hif = __builtin_bit_cast(float, u & 0xFFFF0000u);
    float lof = f - hif;
    unsigned lo = __builtin_bit_cast(unsigned, lof);
    return (u >> 16) | (lo & 0xFFFF0000u);
}

// Gate pre-scale for exp2: i,f,o -> -log2e; g (gate 2) -> -2*log2e.
__device__ __forceinline__ float gate_scale(int g) {
    return (g == 2) ? (-2.0f * L2E) : (-L2E);
}

// U-frag LDS slot: ((cell*4+g)*2+c)*2+hl, address (slot*64+lane)*16B.
// Lane-contiguous b128 reads/writes — the m97 fast path, conflict-free.
__device__ __forceinline__ int uslot(int cell, int g, int c, int hl) {
    return ((cell * 4 + g) * 2 + c) * 2 + hl;
}

// Stage ONE cell's A4 frags into LDS (4 KB). Called by wave 0 only; restaged
// at the warmup->decode transition (off the hot path, behind barriers).
__device__ __forceinline__ void stage_a4(short* __restrict__ a4lds,
                                         const float* __restrict__ Wks,
                                         const float* __restrict__ bvs,
                                         int m, int H, int lane) {
#pragma unroll
    for (int g = 0; g < 4; ++g) {
        const float s = gate_scale(g);
        short whi, wlo, bhi, blo;
        bf_split_rne(Wks[g * 32 + m] * s, whi, wlo);
        bf_split_rne(bvs[g * 32 + m] * s, bhi, blo);
        // A4: [wk_hi, wk_hi, wk_lo, b_hi, b_lo, 0,0,0] on H==0 lanes, else 0.
        bf16x8 a = {whi, whi, wlo, bhi, blo, 0, 0, 0};
        u32x4 z4 = {0u, 0u, 0u, 0u};
        if (H != 0) a = __builtin_bit_cast(bf16x8, z4);
        *(bf16x8*)(a4lds + (g * 64 + lane) * 8) = a;
    }
}

// One LSTM step for 32 batch rows. EXACT R2 (mfma15, verified 389us/4.88e-4)
// scalar activation body; the ONLY change is the MFMA chain: the weight-lo x
// h-hi cross term (Al*Bh) is dropped (8 MFMA + 8 ds_read_b128 fewer / step).
// Al is the RNE residual (~2^-9 relative), so the dropped term is the
// smallest of the three cross products; Ah*Bl (h's truncation residual,
// ~2^-8) is kept. 20 MFMA/step: per gate A4*B4, Ah0*B0l, Ah0*B0h,
// Ah1*B1l, Ah1*B1h.
template <bool NEED_P>
__device__ __forceinline__ float lstm_step32(unsigned xpack,
    const short* __restrict__ ufbase,          // &uflds[cell-base]
    const short* __restrict__ a4cell,          // &a4lds[0]
    bf16x8& B0h, bf16x8& B0l, bf16x8& B1h, bf16x8& B1l,
    float* cs, const float* __restrict__ wdp,  // &wdlds[H][0] (broadcast)
    int lane, int H) {
    // B4 on H==0 lanes: [x_hi, x_lo, x_hi, 1, 1, 0,0,0].
    unsigned w0 = xpack;
    unsigned w1 = (xpack & 0xFFFFu) | 0x3F800000u;
    unsigned w2 = 0x00003F80u;
    if (H != 0) { w0 = 0u; w1 = 0u; w2 = 0u; }
    u32x4 b4u = {w0, w1, w2, 0u};
    const bf16x8 B4 = __builtin_bit_cast(bf16x8, b4u);
    const f32x16 zero16 = {0,0,0,0,0,0,0,0,0,0,0,0,0,0,0,0};

    f32x16 acc[4];
#pragma unroll
    for (int g = 0; g < 4; ++g) {
        const bf16x8 A4g = *(const bf16x8*)(a4cell + (g * 64 + lane) * 8);
        const bf16x8 Ah0 = *(const bf16x8*)(ufbase + (uslot(0, g, 0, 0) * 64 + lane) * 8);
        const bf16x8 Ah1 = *(const bf16x8*)(ufbase + (uslot(0, g, 1, 0) * 64 + lane) * 8);
        f32x16 a = __builtin_amdgcn_mfma_f32_32x32x16_bf16(A4g, B4, zero16, 0, 0, 0);
        a = __builtin_amdgcn_mfma_f32_32x32x16_bf16(Ah0, B0l, a, 0, 0, 0);
        a = __builtin_amdgcn_mfma_f32_32x32x16_bf16(Ah0, B0h, a, 0, 0, 0);
        a = __builtin_amdgcn_mfma_f32_32x32x16_bf16(Ah1, B1l, a, 0, 0, 0);
        a = __builtin_amdgcn_mfma_f32_32x32x16_bf16(Ah1, B1h, a, 0, 0, 0);
        acc[g] = a;
    }

    float pp = 0.0f;
#pragma unroll
    for (int r = 0; r < 16; ++r) {
        float ei = __builtin_amdgcn_exp2f(acc[0][r]);
        float ef = __builtin_amdgcn_exp2f(acc[1][r]);
        float eg = __builtin_amdgcn_exp2f(__builtin_fminf(acc[2][r], ECLAMP));
        float eo = __builtin_amdgcn_exp2f(acc[3][r]);
        float di = 1.0f + ei, df = 1.0f + ef, dg = 1.0f + eg, do_ = 1.0f + eo;
        float ngs = __builtin_fmaf(eg, 2.0f * L2E, -2.0f * L2E);  // -2L2E*(1-eg)
        float t1 = di * dg;
        float t2 = cs[r] * t1;
        float num = __builtin_fmaf(ngs, df, t2);
        float cn = num * __builtin_amdgcn_rcpf(df * t1);          // scaled c'
        cs[r] = cn;
        float ec = __builtin_amdgcn_exp2f(__builtin_fminf(cn, ECLAMP)); // e^-2c
        float h = (1.0f - ec) * __builtin_amdgcn_rcpf(do_ * (1.0f + ec)); // o*tanh(c)
        if constexpr (NEED_P) pp = __builtin_fmaf(h, wdp[r], pp); // LDS broadcast
        unsigned u = __builtin_bit_cast(unsigned, h);
        float hif = __builtin_bit_cast(float, u & 0xFFFF0000u);
        float lof = h - hif;
        short hb = (short)(u >> 16);
        short lb = (short)(__builtin_bit_cast(unsigned, lof) >> 16);
        if (r < 8) { B0h[r] = hb; B0l[r] = lb; }
        else       { B1h[r - 8] = hb; B1l[r - 8] = lb; }
    }
    return pp;
}

// (256,4): LDS 37 KB, arch ~64 + 64 acc VGPR -> 16 waves/CU, grid = 4
// blocks/CU exactly. Counter model (R0-R4, MfmaUtil+VALUBusy==100%
// invariant): the SIMD executes one instruction class at a time, so
// dur == total occupancy cycles. Budget/wave-step at R2: trans 1792 (55%),
// MFMA 896 (27%), VALU ~550 (17%). This round cuts MFMA 28->20 (-256 cyc)
// + 8 ds_reads. Trans floor untouched (5 exp2 + 2 rcp/cell is algebraically
// minimal for this formulation).
__global__ __launch_bounds__(256, 4) void lstm_feedback_mfma19(
    const float* __restrict__ inputs,  // [B, 48]
    const float* __restrict__ Wk_w, const float* __restrict__ Uk_w, const float* __restrict__ b_w,
    const float* __restrict__ Wk_d, const float* __restrict__ Uk_d, const float* __restrict__ b_d,
    const float* __restrict__ Wd, const float* __restrict__ bd,
    float* __restrict__ out,           // [B, 24]
    int B) {
    const int tid = threadIdx.x;       // 4 waves x 32 batch = 128 batch/block
    const int w = tid >> 6;
    const int lane = tid & 63;
    const int m = lane & 31;           // batch column within wave / out-unit row
    const int H = lane >> 5;
    const int mblk = blockIdx.x * 128;
    const long row = (long)(mblk + w * 32 + m);

    __shared__ __align__(16) short uflds[32 * 64 * 8];  // 32 KB: both cells' U-frags
    __shared__ __align__(16) short a4lds[4 * 64 * 8];   // 4 KB: ONE cell's A4
    __shared__ float wdlds[2][16];                      // Wd in D-reg order

    // Waves 0/1 stage cell 0/1: U-frags (pre-scaled, permuted, hi/lo split).
    // (lo slots staged but unread this round — one-time cost, minimal diff.)
    if (w < 2) {
        const float* Uks = w ? Uk_d : Uk_w;
#pragma unroll
        for (int g = 0; g < 4; ++g) {
            const float s = gate_scale(g);
#pragma unroll
            for (int c = 0; c < 2; ++c) {
                bf16x8 ah, al;
#pragma unroll
                for (int j = 0; j < 8; ++j) {
                    const int uin = 16 * c + 4 * H + (j & 3) + 8 * (j >> 2);
                    float wt = Uks[uin * 128 + g * 32 + m] * s;
                    short hb, lb; bf_split_rne(wt, hb, lb);
                    ah[j] = hb; al[j] = lb;
                }
                *(bf16x8*)(uflds + (uslot(w, g, c, 0) * 64 + lane) * 8) = ah;
                *(bf16x8*)(uflds + (uslot(w, g, c, 1) * 64 + lane) * 8) = al;
            }
        }
    }
    // Warmup cell's A4 (wave 0 covers all 64 lanes x 4 gates).
    if (w == 0) stage_a4(a4lds, Wk_w, b_w, m, H, lane);
    // Wd in D-layout order: unit of D reg r is (r&3) + 8*(r>>2) + 4H.
    if (tid < 32) {
        const int r = tid & 15, Hh = tid >> 4;
        wdlds[Hh][r] = Wd[(r & 3) + 8 * (r >> 2) + 4 * Hh];
    }

    u32x4 z4 = {0u, 0u, 0u, 0u};
    bf16x8 B0h = __builtin_bit_cast(bf16x8, z4), B0l = B0h, B1h = B0h, B1l = B0h;
    float cs[16];
#pragma unroll
    for (int r = 0; r < 16; ++r) cs[r] = 0.0f;

    __syncthreads();  // uflds + a4lds + wdlds visible

    const short* __restrict__ uf_w = uflds;
    const short* __restrict__ uf_d = uflds + 16 * 64 * 8;
    const float* __restrict__ wdp = &wdlds[H][0];

    // ---- warmup: per-lane x from global (L2-resident), one-step prefetch ----
    float xc = inputs[row * TSTEPS + 0];
    for (int t = 0; t < TSTEPS - 1; ++t) {
        float xn = inputs[row * TSTEPS + t + 1];  // issued before the step body
        asm volatile("" ::: "memory");  // keep LDS frag reads in-loop (anti-LICM)
        lstm_step32<false>(split_pack(xc), uf_w, a4lds,
                           B0h, B0l, B1h, B1l, cs, wdp, lane, H);
        xc = xn;
    }

    const float bdv = bd[0];

    // ---- last warmup step with pred fold; single-shuffle reduce ----
    asm volatile("" ::: "memory");
    float p = lstm_step32<true>(split_pack(xc), uf_w, a4lds,
                                B0h, B0l, B1h, B1l, cs, wdp, lane, H);
    p += __shfl_xor(p, 32);
    p += bdv;                          // both H lanes of batch m hold pred(batch m)
    if (H == 0) out[row * OUT_STEPS + 0] = p;

    // ---- transition: restage A4 for the decode cell (once, off hot path) ----
    __syncthreads();                   // all waves done reading warmup A4
    if (w == 0) stage_a4(a4lds, Wk_d, b_d, m, H, lane);
    __syncthreads();                   // decode A4 visible

    // ---- decode: U pointer swap; A4 already swapped in LDS ----
    for (int s = 1; s < OUT_STEPS; ++s) {
        asm volatile("" ::: "memory");
        p = lstm_step32<true>(split_pack(p), uf_d, a4lds,
                              B0h, B0l, B1h, B1l, cs, wdp, lane, H);
        p += __shfl_xor(p, 32);
        p += bdv;
        if (H == 0) out[row * OUT_STEPS + s] = p;
    }
}

extern "C" void kernel_launch(void* const* d_in, const int* in_sizes, int n_in,
                              void* d_out, int out_size, void* d_ws, size_t ws_size,
                              hipStream_t stream) {
    const float* inputs = (const float*)d_in[0];
    const float* Wk_w   = (const float*)d_in[1];
    const float* Uk_w   = (const float*)d_in[2];
    const float* b_w    = (const float*)d_in[3];
    const float* Wk_d   = (const float*)d_in[4];
    const float* Uk_d   = (const float*)d_in[5];
    const float* b_d    = (const float*)d_in[6];
    const float* Wd     = (const float*)d_in[7];
    const float* bd     = (const float*)d_in[8];
    float* out = (float*)d_out;

    const int B = in_sizes[0] / TSTEPS;
    const int grid = (B + 127) / 128;  // 128 batch rows per 256-thread block
    lstm_feedback_mfma19<<<grid, 256, 0, stream>>>(
        inputs, Wk_w, Uk_w, b_w, Wk_d, Uk_d, b_d, Wd, bd, out, B);
}

// Round 7
// 359.048 us; speedup vs baseline: 1.2765x; 1.0877x over previous
//
#include <hip/hip_runtime.h>

#define TSTEPS 48
#define OUT_STEPS 24
#define L2E 1.44269504088896340736f
#define ECLAMP 30.0f

typedef short bf16x8 __attribute__((ext_vector_type(8)));
typedef float f32x16 __attribute__((ext_vector_type(16)));
typedef unsigned int u32x4 __attribute__((ext_vector_type(4)));

// RNE bf16 hi + truncated-residual lo (weights; off hot path).
__device__ __forceinline__ void bf_split_rne(float f, short& hi, short& lo) {
    unsigned u = __builtin_bit_cast(unsigned, f);
    unsigned r = u + 0x7FFFu + ((u >> 16) & 1u);
    unsigned short hb = (unsigned short)(r >> 16);
    float hif = __builtin_bit_cast(float, (unsigned)hb << 16);
    float lof = f - hif;
    unsigned short lb = (unsigned short)(__builtin_bit_cast(unsigned, lof) >> 16);
    hi = (short)hb; lo = (short)lb;
}

// Truncation split packed into one dword: low16 = hi-bf16, high16 = lo-bf16.
// (x keeps the double-bf16 path through B4 — costs nothing extra.)
__device__ __forceinline__ unsigned split_pack(float f) {
    unsigned u = __builtin_bit_cast(unsigned, f);
    float hif = __builtin_bit_cast(float, u & 0xFFFF0000u);
    float lof = f - hif;
    unsigned lo = __builtin_bit_cast(unsigned, lof);
    return (u >> 16) | (lo & 0xFFFF0000u);
}

// Gate pre-scale for exp2: i,f,o -> -log2e; g (gate 2) -> -2*log2e.
__device__ __forceinline__ float gate_scale(int g) {
    return (g == 2) ? (-2.0f * L2E) : (-L2E);
}

// U-frag LDS slot: ((cell*4+g)*2+c)*2+hl, address (slot*64+lane)*16B.
// Lane-contiguous b128 reads/writes — the m97 fast path, conflict-free.
__device__ __forceinline__ int uslot(int cell, int g, int c, int hl) {
    return ((cell * 4 + g) * 2 + c) * 2 + hl;
}

// Stage ONE cell's A4 frags into LDS (4 KB). Called by wave 0 only; restaged
// at the warmup->decode transition (off the hot path, behind barriers).
__device__ __forceinline__ void stage_a4(short* __restrict__ a4lds,
                                         const float* __restrict__ Wks,
                                         const float* __restrict__ bvs,
                                         int m, int H, int lane) {
#pragma unroll
    for (int g = 0; g < 4; ++g) {
        const float s = gate_scale(g);
        short whi, wlo, bhi, blo;
        bf_split_rne(Wks[g * 32 + m] * s, whi, wlo);
        bf_split_rne(bvs[g * 32 + m] * s, bhi, blo);
        // A4: [wk_hi, wk_hi, wk_lo, b_hi, b_lo, 0,0,0] on H==0 lanes, else 0.
        bf16x8 a = {whi, whi, wlo, bhi, blo, 0, 0, 0};
        u32x4 z4 = {0u, 0u, 0u, 0u};
        if (H != 0) a = __builtin_bit_cast(bf16x8, z4);
        *(bf16x8*)(a4lds + (g * 64 + lane) * 8) = a;
    }
}

// One LSTM step for 32 batch rows. Scalar activation body VERBATIM from the
// verified R2/R6 form. MFMA chain (R7): h carried as a SINGLE RNE-rounded
// bf16 frag per K-half (B0, B1) — the Ah*Bl h-residual term is dropped
// (R6 proved the same-magnitude Al*Bh term was absmax-neutral). RNE (not
// truncation) keeps the per-step h error unbiased so it random-walks, not
// drifts, over the 71-step recurrence. 12 MFMA/step: per gate A4*B4,
// Ah0*B0, Ah1*B1. Also saves the per-row lo-split VALU ops and 8
// ds_read_b128/step.
template <bool NEED_P>
__device__ __forceinline__ float lstm_step32(unsigned xpack,
    const short* __restrict__ ufbase,          // &uflds[cell-base]
    const short* __restrict__ a4cell,          // &a4lds[0]
    bf16x8& B0, bf16x8& B1,
    float* cs, const float* __restrict__ wdp,  // &wdlds[H][0] (broadcast)
    int lane, int H) {
    // B4 on H==0 lanes: [x_hi, x_lo, x_hi, 1, 1, 0,0,0].
    unsigned w0 = xpack;
    unsigned w1 = (xpack & 0xFFFFu) | 0x3F800000u;
    unsigned w2 = 0x00003F80u;
    if (H != 0) { w0 = 0u; w1 = 0u; w2 = 0u; }
    u32x4 b4u = {w0, w1, w2, 0u};
    const bf16x8 B4 = __builtin_bit_cast(bf16x8, b4u);
    const f32x16 zero16 = {0,0,0,0,0,0,0,0,0,0,0,0,0,0,0,0};

    f32x16 acc[4];
#pragma unroll
    for (int g = 0; g < 4; ++g) {
        const bf16x8 A4g = *(const bf16x8*)(a4cell + (g * 64 + lane) * 8);
        const bf16x8 Ah0 = *(const bf16x8*)(ufbase + (uslot(0, g, 0, 0) * 64 + lane) * 8);
        const bf16x8 Ah1 = *(const bf16x8*)(ufbase + (uslot(0, g, 1, 0) * 64 + lane) * 8);
        f32x16 a = __builtin_amdgcn_mfma_f32_32x32x16_bf16(A4g, B4, zero16, 0, 0, 0);
        a = __builtin_amdgcn_mfma_f32_32x32x16_bf16(Ah0, B0, a, 0, 0, 0);
        a = __builtin_amdgcn_mfma_f32_32x32x16_bf16(Ah1, B1, a, 0, 0, 0);
        acc[g] = a;
    }

    float pp = 0.0f;
#pragma unroll
    for (int r = 0; r < 16; ++r) {
        float ei = __builtin_amdgcn_exp2f(acc[0][r]);
        float ef = __builtin_amdgcn_exp2f(acc[1][r]);
        float eg = __builtin_amdgcn_exp2f(__builtin_fminf(acc[2][r], ECLAMP));
        float eo = __builtin_amdgcn_exp2f(acc[3][r]);
        float di = 1.0f + ei, df = 1.0f + ef, dg = 1.0f + eg, do_ = 1.0f + eo;
        float ngs = __builtin_fmaf(eg, 2.0f * L2E, -2.0f * L2E);  // -2L2E*(1-eg)
        float t1 = di * dg;
        float t2 = cs[r] * t1;
        float num = __builtin_fmaf(ngs, df, t2);
        float cn = num * __builtin_amdgcn_rcpf(df * t1);          // scaled c'
        cs[r] = cn;
        float ec = __builtin_amdgcn_exp2f(__builtin_fminf(cn, ECLAMP)); // e^-2c
        float h = (1.0f - ec) * __builtin_amdgcn_rcpf(do_ * (1.0f + ec)); // o*tanh(c)
        if constexpr (NEED_P) pp = __builtin_fmaf(h, wdp[r], pp); // LDS broadcast
        // h -> bf16 RNE (unbiased; no lo residual carried).
        unsigned u = __builtin_bit_cast(unsigned, h);
        unsigned rb = u + 0x7FFFu + ((u >> 16) & 1u);
        short hb = (short)(rb >> 16);
        if (r < 8) B0[r] = hb;
        else       B1[r - 8] = hb;
    }
    return pp;
}

// (256,4): LDS 37 KB, arch ~60 + 64 acc VGPR -> 16 waves/CU, grid = 4
// blocks/CU exactly. Counter model (R0-R6, serial-issue: dur == total
// occupancy cycles; MfmaUtil+VALUBusy ~= 100%). Budget/wave-step at R6:
// trans 1792 (57%), MFMA 640 (21%), VALU ~550, ds ~140. This round cuts
// MFMA 20->12 (-256 cyc), per-row lo-split VALU (-~120 cyc), 8 ds_reads.
// Trans floor untouched (5 exp2 + 2 rcp/cell, algebraically minimal here).
__global__ __launch_bounds__(256, 4) void lstm_feedback_mfma20(
    const float* __restrict__ inputs,  // [B, 48]
    const float* __restrict__ Wk_w, const float* __restrict__ Uk_w, const float* __restrict__ b_w,
    const float* __restrict__ Wk_d, const float* __restrict__ Uk_d, const float* __restrict__ b_d,
    const float* __restrict__ Wd, const float* __restrict__ bd,
    float* __restrict__ out,           // [B, 24]
    int B) {
    const int tid = threadIdx.x;       // 4 waves x 32 batch = 128 batch/block
    const int w = tid >> 6;
    const int lane = tid & 63;
    const int m = lane & 31;           // batch column within wave / out-unit row
    const int H = lane >> 5;
    const int mblk = blockIdx.x * 128;
    const long row = (long)(mblk + w * 32 + m);

    __shared__ __align__(16) short uflds[32 * 64 * 8];  // 32 KB: both cells' U-frags
    __shared__ __align__(16) short a4lds[4 * 64 * 8];   // 4 KB: ONE cell's A4
    __shared__ float wdlds[2][16];                      // Wd in D-reg order

    // Waves 0/1 stage cell 0/1: U-frags (pre-scaled, permuted, hi/lo split).
    // (lo slots staged but unread — off hot path, minimal diff.)
    if (w < 2) {
        const float* Uks = w ? Uk_d : Uk_w;
#pragma unroll
        for (int g = 0; g < 4; ++g) {
            const float s = gate_scale(g);
#pragma unroll
            for (int c = 0; c < 2; ++c) {
                bf16x8 ah, al;
#pragma unroll
                for (int j = 0; j < 8; ++j) {
                    const int uin = 16 * c + 4 * H + (j & 3) + 8 * (j >> 2);
                    float wt = Uks[uin * 128 + g * 32 + m] * s;
                    short hb, lb; bf_split_rne(wt, hb, lb);
                    ah[j] = hb; al[j] = lb;
                }
                *(bf16x8*)(uflds + (uslot(w, g, c, 0) * 64 + lane) * 8) = ah;
                *(bf16x8*)(uflds + (uslot(w, g, c, 1) * 64 + lane) * 8) = al;
            }
        }
    }
    // Warmup cell's A4 (wave 0 covers all 64 lanes x 4 gates).
    if (w == 0) stage_a4(a4lds, Wk_w, b_w, m, H, lane);
    // Wd in D-layout order: unit of D reg r is (r&3) + 8*(r>>2) + 4H.
    if (tid < 32) {
        const int r = tid & 15, Hh = tid >> 4;
        wdlds[Hh][r] = Wd[(r & 3) + 8 * (r >> 2) + 4 * Hh];
    }

    u32x4 z4 = {0u, 0u, 0u, 0u};
    bf16x8 B0 = __builtin_bit_cast(bf16x8, z4), B1 = B0;
    float cs[16];
#pragma unroll
    for (int r = 0; r < 16; ++r) cs[r] = 0.0f;

    __syncthreads();  // uflds + a4lds + wdlds visible

    const short* __restrict__ uf_w = uflds;
    const short* __restrict__ uf_d = uflds + 16 * 64 * 8;
    const float* __restrict__ wdp = &wdlds[H][0];

    // ---- warmup: per-lane x from global (L2-resident), one-step prefetch ----
    float xc = inputs[row * TSTEPS + 0];
    for (int t = 0; t < TSTEPS - 1; ++t) {
        float xn = inputs[row * TSTEPS + t + 1];  // issued before the step body
        asm volatile("" ::: "memory");  // keep LDS frag reads in-loop (anti-LICM)
        lstm_step32<false>(split_pack(xc), uf_w, a4lds,
                           B0, B1, cs, wdp, lane, H);
        xc = xn;
    }

    const float bdv = bd[0];

    // ---- last warmup step with pred fold; single-shuffle reduce ----
    asm volatile("" ::: "memory");
    float p = lstm_step32<true>(split_pack(xc), uf_w, a4lds,
                                B0, B1, cs, wdp, lane, H);
    p += __shfl_xor(p, 32);
    p += bdv;                          // both H lanes of batch m hold pred(batch m)
    if (H == 0) out[row * OUT_STEPS + 0] = p;

    // ---- transition: restage A4 for the decode cell (once, off hot path) ----
    __syncthreads();                   // all waves done reading warmup A4
    if (w == 0) stage_a4(a4lds, Wk_d, b_d, m, H, lane);
    __syncthreads();                   // decode A4 visible

    // ---- decode: U pointer swap; A4 already swapped in LDS ----
    for (int s = 1; s < OUT_STEPS; ++s) {
        asm volatile("" ::: "memory");
        p = lstm_step32<true>(split_pack(p), uf_d, a4lds,
                              B0, B1, cs, wdp, lane, H);
        p += __shfl_xor(p, 32);
        p += bdv;
        if (H == 0) out[row * OUT_STEPS + s] = p;
    }
}

extern "C" void kernel_launch(void* const* d_in, const int* in_sizes, int n_in,
                              void* d_out, int out_size, void* d_ws, size_t ws_size,
                              hipStream_t stream) {
    const float* inputs = (const float*)d_in[0];
    const float* Wk_w   = (const float*)d_in[1];
    const float* Uk_w   = (const float*)d_in[2];
    const float* b_w    = (const float*)d_in[3];
    const float* Wk_d   = (const float*)d_in[4];
    const float* Uk_d   = (const float*)d_in[5];
    const float* b_d    = (const float*)d_in[6];
    const float* Wd     = (const float*)d_in[7];
    const float* bd     = (const float*)d_in[8];
    float* out = (float*)d_out;

    const int B = in_sizes[0] / TSTEPS;
    const int grid = (B + 127) / 128;  // 128 batch rows per 256-thread block
    lstm_feedback_mfma20<<<grid, 256, 0, stream>>>(
        inputs, Wk_w, Uk_w, b_w, Wk_d, Uk_d, b_d, Wd, bd, out, B);
}

// Round 8
// 348.464 us; speedup vs baseline: 1.3153x; 1.0304x over previous
//
#include <hip/hip_runtime.h>

#define TSTEPS 48
#define OUT_STEPS 24
#define L2E 1.44269504088896340736f
#define ECLAMP 30.0f

typedef short bf16x8 __attribute__((ext_vector_type(8)));
typedef float f32x16 __attribute__((ext_vector_type(16)));
typedef unsigned int u32x4 __attribute__((ext_vector_type(4)));

// RNE bf16 hi + truncated-residual lo (weights; off hot path).
__device__ __forceinline__ void bf_split_rne(float f, short& hi, short& lo) {
    unsigned u = __builtin_bit_cast(unsigned, f);
    unsigned r = u + 0x7FFFu + ((u >> 16) & 1u);
    unsigned short hb = (unsigned short)(r >> 16);
    float hif = __builtin_bit_cast(float, (unsigned)hb << 16);
    float lof = f - hif;
    unsigned short lb = (unsigned short)(__builtin_bit_cast(unsigned, lof) >> 16);
    hi = (short)hb; lo = (short)lb;
}

// Truncation split packed into one dword: low16 = hi-bf16, high16 = lo-bf16.
// (x keeps the double-bf16 path through B4 — costs nothing extra.)
__device__ __forceinline__ unsigned split_pack(float f) {
    unsigned u = __builtin_bit_cast(unsigned, f);
    float hif = __builtin_bit_cast(float, u & 0xFFFF0000u);
    float lof = f - hif;
    unsigned lo = __builtin_bit_cast(unsigned, lof);
    return (u >> 16) | (lo & 0xFFFF0000u);
}

// Gate pre-scale for exp2: i,f,o -> -log2e; g (gate 2) -> -2*log2e.
__device__ __forceinline__ float gate_scale(int g) {
    return (g == 2) ? (-2.0f * L2E) : (-L2E);
}

// U-frag LDS slot (hi-only since R7): (cell*4+g)*2+c, addr (slot*64+lane)*16B.
// Lane-contiguous b128 reads/writes — conflict-free.
__device__ __forceinline__ int uslot(int cell, int g, int c) {
    return (cell * 4 + g) * 2 + c;
}

// Stage ONE cell's A4 frags into LDS (4 KB). Called by wave 0 only; restaged
// at the warmup->decode transition (off the hot path, behind barriers).
__device__ __forceinline__ void stage_a4(short* __restrict__ a4lds,
                                         const float* __restrict__ Wks,
                                         const float* __restrict__ bvs,
                                         int m, int H, int lane) {
#pragma unroll
    for (int g = 0; g < 4; ++g) {
        const float s = gate_scale(g);
        short whi, wlo, bhi, blo;
        bf_split_rne(Wks[g * 32 + m] * s, whi, wlo);
        bf_split_rne(bvs[g * 32 + m] * s, bhi, blo);
        // A4: [wk_hi, wk_hi, wk_lo, b_hi, b_lo, 0,0,0] on H==0 lanes, else 0.
        bf16x8 a = {whi, whi, wlo, bhi, blo, 0, 0, 0};
        u32x4 z4 = {0u, 0u, 0u, 0u};
        if (H != 0) a = __builtin_bit_cast(bf16x8, z4);
        *(bf16x8*)(a4lds + (g * 64 + lane) * 8) = a;
    }
}

// One LSTM step for 32 batch rows. Scalar activation body VERBATIM from the
// verified R2/R6/R7 form. 12 MFMA/step (R7 structure): per gate A4*B4,
// Ah0*B0, Ah1*B1 with h carried as single RNE bf16 per unit.
// R8 delta: h->bf16 via ONE v_cvt_pk_bf16_f32 per row PAIR (RNE, T12 recipe,
// low half = first operand = even row — the R3-verified packed layout),
// replacing ~5 manual int ops + insert per row. B-frags held as u32x4.
template <bool NEED_P>
__device__ __forceinline__ float lstm_step32(unsigned xpack,
    const short* __restrict__ ufbase,          // &uflds[cell-base]
    const short* __restrict__ a4cell,          // &a4lds[0]
    u32x4& B0, u32x4& B1,
    float* cs, const float* __restrict__ wdp,  // &wdlds[H][0] (broadcast)
    int lane, int H) {
    // B4 on H==0 lanes: [x_hi, x_lo, x_hi, 1, 1, 0,0,0].
    unsigned w0 = xpack;
    unsigned w1 = (xpack & 0xFFFFu) | 0x3F800000u;
    unsigned w2 = 0x00003F80u;
    if (H != 0) { w0 = 0u; w1 = 0u; w2 = 0u; }
    u32x4 b4u = {w0, w1, w2, 0u};
    const bf16x8 B4 = __builtin_bit_cast(bf16x8, b4u);
    const bf16x8 b0 = __builtin_bit_cast(bf16x8, B0);
    const bf16x8 b1 = __builtin_bit_cast(bf16x8, B1);
    const f32x16 zero16 = {0,0,0,0,0,0,0,0,0,0,0,0,0,0,0,0};

    f32x16 acc[4];
#pragma unroll
    for (int g = 0; g < 4; ++g) {
        const bf16x8 A4g = *(const bf16x8*)(a4cell + (g * 64 + lane) * 8);
        const bf16x8 Ah0 = *(const bf16x8*)(ufbase + (uslot(0, g, 0) * 64 + lane) * 8);
        const bf16x8 Ah1 = *(const bf16x8*)(ufbase + (uslot(0, g, 1) * 64 + lane) * 8);
        f32x16 a = __builtin_amdgcn_mfma_f32_32x32x16_bf16(A4g, B4, zero16, 0, 0, 0);
        a = __builtin_amdgcn_mfma_f32_32x32x16_bf16(Ah0, b0, a, 0, 0, 0);
        a = __builtin_amdgcn_mfma_f32_32x32x16_bf16(Ah1, b1, a, 0, 0, 0);
        acc[g] = a;
    }

    float pp = 0.0f;
    float he = 0.0f;                   // even-row h, packed on the odd row
#pragma unroll
    for (int r = 0; r < 16; ++r) {
        float ei = __builtin_amdgcn_exp2f(acc[0][r]);
        float ef = __builtin_amdgcn_exp2f(acc[1][r]);
        float eg = __builtin_amdgcn_exp2f(__builtin_fminf(acc[2][r], ECLAMP));
        float eo = __builtin_amdgcn_exp2f(acc[3][r]);
        float di = 1.0f + ei, df = 1.0f + ef, dg = 1.0f + eg, do_ = 1.0f + eo;
        float ngs = __builtin_fmaf(eg, 2.0f * L2E, -2.0f * L2E);  // -2L2E*(1-eg)
        float t1 = di * dg;
        float t2 = cs[r] * t1;
        float num = __builtin_fmaf(ngs, df, t2);
        float cn = num * __builtin_amdgcn_rcpf(df * t1);          // scaled c'
        cs[r] = cn;
        float ec = __builtin_amdgcn_exp2f(__builtin_fminf(cn, ECLAMP)); // e^-2c
        float h = (1.0f - ec) * __builtin_amdgcn_rcpf(do_ * (1.0f + ec)); // o*tanh(c)
        if constexpr (NEED_P) pp = __builtin_fmaf(h, wdp[r], pp); // LDS broadcast
        if ((r & 1) == 0) {
            he = h;
        } else {
            unsigned d;  // low16 = bf16_rne(he) [even], high16 = bf16_rne(h) [odd]
            asm("v_cvt_pk_bf16_f32 %0, %1, %2" : "=v"(d) : "v"(he), "v"(h));
            const int q = r >> 1;      // compile-time after unroll
            if (q < 4) B0[q] = d;
            else       B1[q - 4] = d;
        }
    }
    return pp;
}

// (256,4): LDS ~21 KB, arch ~60 + 64 acc VGPR -> 16 waves/CU, grid = 4
// blocks/CU exactly. Counter model (R0-R7, serial-issue; per-SIMD VALU
// demand ~90% of period): only lever left is plain-VALU count. R8 cuts the
// per-row RNE pack (~5 ops) to one cvt_pk per pair and halves uflds (lo
// slots dead since R7). Trans floor (5 exp2 + 2 rcp/cell) untouched —
// that floor is ~255 us; we are converging on it.
__global__ __launch_bounds__(256, 4) void lstm_feedback_mfma21(
    const float* __restrict__ inputs,  // [B, 48]
    const float* __restrict__ Wk_w, const float* __restrict__ Uk_w, const float* __restrict__ b_w,
    const float* __restrict__ Wk_d, const float* __restrict__ Uk_d, const float* __restrict__ b_d,
    const float* __restrict__ Wd, const float* __restrict__ bd,
    float* __restrict__ out,           // [B, 24]
    int B) {
    const int tid = threadIdx.x;       // 4 waves x 32 batch = 128 batch/block
    const int w = tid >> 6;
    const int lane = tid & 63;
    const int m = lane & 31;           // batch column within wave / out-unit row
    const int H = lane >> 5;
    const int mblk = blockIdx.x * 128;
    const long row = (long)(mblk + w * 32 + m);

    __shared__ __align__(16) short uflds[16 * 64 * 8];  // 16 KB: both cells' hi U-frags
    __shared__ __align__(16) short a4lds[4 * 64 * 8];   // 4 KB: ONE cell's A4
    __shared__ float wdlds[2][16];                      // Wd in D-reg order

    // Waves 0/1 stage cell 0/1: hi U-frags (pre-scaled, permuted, RNE).
    if (w < 2) {
        const float* Uks = w ? Uk_d : Uk_w;
#pragma unroll
        for (int g = 0; g < 4; ++g) {
            const float s = gate_scale(g);
#pragma unroll
            for (int c = 0; c < 2; ++c) {
                bf16x8 ah;
#pragma unroll
                for (int j = 0; j < 8; ++j) {
                    const int uin = 16 * c + 4 * H + (j & 3) + 8 * (j >> 2);
                    float wt = Uks[uin * 128 + g * 32 + m] * s;
                    short hb, lb; bf_split_rne(wt, hb, lb);
                    ah[j] = hb;
                }
                *(bf16x8*)(uflds + (uslot(w, g, c) * 64 + lane) * 8) = ah;
            }
        }
    }
    // Warmup cell's A4 (wave 0 covers all 64 lanes x 4 gates).
    if (w == 0) stage_a4(a4lds, Wk_w, b_w, m, H, lane);
    // Wd in D-layout order: unit of D reg r is (r&3) + 8*(r>>2) + 4H.
    if (tid < 32) {
        const int r = tid & 15, Hh = tid >> 4;
        wdlds[Hh][r] = Wd[(r & 3) + 8 * (r >> 2) + 4 * Hh];
    }

    u32x4 z4 = {0u, 0u, 0u, 0u};
    u32x4 B0 = z4, B1 = z4;
    float cs[16];
#pragma unroll
    for (int r = 0; r < 16; ++r) cs[r] = 0.0f;

    __syncthreads();  // uflds + a4lds + wdlds visible

    const short* __restrict__ uf_w = uflds;
    const short* __restrict__ uf_d = uflds + 8 * 64 * 8;
    const float* __restrict__ wdp = &wdlds[H][0];

    // ---- warmup: per-lane x from global (L2-resident), one-step prefetch ----
    float xc = inputs[row * TSTEPS + 0];
    for (int t = 0; t < TSTEPS - 1; ++t) {
        float xn = inputs[row * TSTEPS + t + 1];  // issued before the step body
        asm volatile("" ::: "memory");  // keep LDS frag reads in-loop (anti-LICM)
        lstm_step32<false>(split_pack(xc), uf_w, a4lds,
                           B0, B1, cs, wdp, lane, H);
        xc = xn;
    }

    const float bdv = bd[0];

    // ---- last warmup step with pred fold; single-shuffle reduce ----
    asm volatile("" ::: "memory");
    float p = lstm_step32<true>(split_pack(xc), uf_w, a4lds,
                                B0, B1, cs, wdp, lane, H);
    p += __shfl_xor(p, 32);
    p += bdv;                          // both H lanes of batch m hold pred(batch m)
    if (H == 0) out[row * OUT_STEPS + 0] = p;

    // ---- transition: restage A4 for the decode cell (once, off hot path) ----
    __syncthreads();                   // all waves done reading warmup A4
    if (w == 0) stage_a4(a4lds, Wk_d, b_d, m, H, lane);
    __syncthreads();                   // decode A4 visible

    // ---- decode: U pointer swap; A4 already swapped in LDS ----
    for (int s = 1; s < OUT_STEPS; ++s) {
        asm volatile("" ::: "memory");
        p = lstm_step32<true>(split_pack(p), uf_d, a4lds,
                              B0, B1, cs, wdp, lane, H);
        p += __shfl_xor(p, 32);
        p += bdv;
        if (H == 0) out[row * OUT_STEPS + s] = p;
    }
}

extern "C" void kernel_launch(void* const* d_in, const int* in_sizes, int n_in,
                              void* d_out, int out_size, void* d_ws, size_t ws_size,
                              hipStream_t stream) {
    const float* inputs = (const float*)d_in[0];
    const float* Wk_w   = (const float*)d_in[1];
    const float* Uk_w   = (const float*)d_in[2];
    const float* b_w    = (const float*)d_in[3];
    const float* Wk_d   = (const float*)d_in[4];
    const float* Uk_d   = (const float*)d_in[5];
    const float* b_d    = (const float*)d_in[6];
    const float* Wd     = (const float*)d_in[7];
    const float* bd     = (const float*)d_in[8];
    float* out = (float*)d_out;

    const int B = in_sizes[0] / TSTEPS;
    const int grid = (B + 127) / 128;  // 128 batch rows per 256-thread block
    lstm_feedback_mfma21<<<grid, 256, 0, stream>>>(
        inputs, Wk_w, Uk_w, b_w, Wk_d, Uk_d, b_d, Wd, bd, out, B);
}

// Round 9
// 318.174 us; speedup vs baseline: 1.4405x; 1.0952x over previous
//
#include <hip/hip_runtime.h>

#define TSTEPS 48
#define OUT_STEPS 24
#define L2E 1.44269504088896340736f
#define ECLAMP 30.0f

typedef short bf16x8 __attribute__((ext_vector_type(8)));
typedef float f32x16 __attribute__((ext_vector_type(16)));
typedef float f32x4 __attribute__((ext_vector_type(4)));
typedef unsigned int u32x4 __attribute__((ext_vector_type(4)));

// RNE bf16 hi + truncated-residual lo (weights; off hot path).
__device__ __forceinline__ void bf_split_rne(float f, short& hi, short& lo) {
    unsigned u = __builtin_bit_cast(unsigned, f);
    unsigned r = u + 0x7FFFu + ((u >> 16) & 1u);
    unsigned short hb = (unsigned short)(r >> 16);
    float hif = __builtin_bit_cast(float, (unsigned)hb << 16);
    float lof = f - hif;
    unsigned short lb = (unsigned short)(__builtin_bit_cast(unsigned, lof) >> 16);
    hi = (short)hb; lo = (short)lb;
}

// Gate pre-scale for exp2: i,f,o -> -log2e; g (gate 2) -> -2*log2e.
__device__ __forceinline__ float gate_scale(int g) {
    return (g == 2) ? (-2.0f * L2E) : (-L2E);
}

// U-frag LDS slot (hi-only since R7): (cell*4+g)*2+c, addr (slot*64+lane)*16B.
// Lane-contiguous b128 reads/writes — conflict-free.
__device__ __forceinline__ int uslot(int cell, int g, int c) {
    return (cell * 4 + g) * 2 + c;
}

// Stage ONE cell's A4 frags into LDS (4 KB). Called by wave 0 only; restaged
// at the warmup->decode transition (off the hot path, behind barriers).
// R9 layout: [wk_hi, wk_lo, b_hi, b_lo, 0,0,0,0] paired with B4 = [x,x,1,1]:
// products (wk_hi+wk_lo)*x_rne + b_hi + b_lo. Error vs old double-double x
// path ~2^-9*wk*x ~ 1e-5 — same class R6/R7/R8 proved absmax-neutral.
__device__ __forceinline__ void stage_a4(short* __restrict__ a4lds,
                                         const float* __restrict__ Wks,
                                         const float* __restrict__ bvs,
                                         int m, int H, int lane) {
#pragma unroll
    for (int g = 0; g < 4; ++g) {
        const float s = gate_scale(g);
        short whi, wlo, bhi, blo;
        bf_split_rne(Wks[g * 32 + m] * s, whi, wlo);
        bf_split_rne(bvs[g * 32 + m] * s, bhi, blo);
        bf16x8 a = {whi, wlo, bhi, blo, 0, 0, 0, 0};
        u32x4 z4 = {0u, 0u, 0u, 0u};
        if (H != 0) a = __builtin_bit_cast(bf16x8, z4);
        *(bf16x8*)(a4lds + (g * 64 + lane) * 8) = a;
    }
}

// One LSTM step for 32 batch rows. 12 MFMA/step (R7 structure): per gate
// A4*B4, Ah0*B0, Ah1*B1; h carried as RNE bf16 (cvt_pk, R8-verified).
// R9 deltas (op-shaving only, math class unchanged):
//  - B4 from ONE v_cvt_pk_bf16_f32(x,x): [x,x,1,1] (split_pack gone)
//  - h epilogue fma-contracted: den=fma(ec,do,do); h=fma(-ec,inv,inv)
//  - g-gate fmin dropped (|acc_g| <= ~19 << 128 by weight/state bounds;
//    the c-path fmin stays — that's the one with real overflow exposure)
//  - Wd read as float4 (4x ds_read_b128 vs 16x b32)
template <bool NEED_P>
__device__ __forceinline__ float lstm_step32(float x,
    const short* __restrict__ ufbase,          // &uflds[cell-base]
    const short* __restrict__ a4cell,          // &a4lds[0]
    u32x4& B0, u32x4& B1,
    float* cs, const float* __restrict__ wdp,  // &wdlds[H][0] (broadcast)
    int lane, unsigned hmask) {
    // B4 on H==0 lanes: [x_rne, x_rne, 1, 1, 0,0,0,0].
    unsigned xr;
    asm("v_cvt_pk_bf16_f32 %0, %1, %2" : "=v"(xr) : "v"(x), "v"(x));
    unsigned w0 = xr & hmask;
    unsigned w1 = 0x3F803F80u & hmask;
    u32x4 b4u = {w0, w1, 0u, 0u};
    const bf16x8 B4 = __builtin_bit_cast(bf16x8, b4u);
    const bf16x8 b0 = __builtin_bit_cast(bf16x8, B0);
    const bf16x8 b1 = __builtin_bit_cast(bf16x8, B1);
    const f32x16 zero16 = {0,0,0,0,0,0,0,0,0,0,0,0,0,0,0,0};

    f32x16 acc[4];
#pragma unroll
    for (int g = 0; g < 4; ++g) {
        const bf16x8 A4g = *(const bf16x8*)(a4cell + (g * 64 + lane) * 8);
        const bf16x8 Ah0 = *(const bf16x8*)(ufbase + (uslot(0, g, 0) * 64 + lane) * 8);
        const bf16x8 Ah1 = *(const bf16x8*)(ufbase + (uslot(0, g, 1) * 64 + lane) * 8);
        f32x16 a = __builtin_amdgcn_mfma_f32_32x32x16_bf16(A4g, B4, zero16, 0, 0, 0);
        a = __builtin_amdgcn_mfma_f32_32x32x16_bf16(Ah0, b0, a, 0, 0, 0);
        a = __builtin_amdgcn_mfma_f32_32x32x16_bf16(Ah1, b1, a, 0, 0, 0);
        acc[g] = a;
    }

    float pp = 0.0f;
    float he = 0.0f;                   // even-row h, packed on the odd row
    f32x4 wq = {0.0f, 0.0f, 0.0f, 0.0f};
#pragma unroll
    for (int r = 0; r < 16; ++r) {
        float ei = __builtin_amdgcn_exp2f(acc[0][r]);
        float ef = __builtin_amdgcn_exp2f(acc[1][r]);
        float eg = __builtin_amdgcn_exp2f(acc[2][r]);               // fmin dropped
        float eo = __builtin_amdgcn_exp2f(acc[3][r]);
        float di = 1.0f + ei, df = 1.0f + ef, dg = 1.0f + eg, do_ = 1.0f + eo;
        float ngs = __builtin_fmaf(eg, 2.0f * L2E, -2.0f * L2E);  // -2L2E*(1-eg)
        float t1 = di * dg;
        float t2 = cs[r] * t1;
        float num = __builtin_fmaf(ngs, df, t2);
        float cn = num * __builtin_amdgcn_rcpf(df * t1);          // scaled c'
        cs[r] = cn;
        float ec = __builtin_amdgcn_exp2f(__builtin_fminf(cn, ECLAMP)); // e^-2c
        float den = __builtin_fmaf(ec, do_, do_);                 // do*(1+ec)
        float inv = __builtin_amdgcn_rcpf(den);
        float h = __builtin_fmaf(-ec, inv, inv);                  // (1-ec)*inv
        if constexpr (NEED_P) {
            if ((r & 3) == 0) wq = *(const f32x4*)(wdp + r);      // ds_read_b128
            pp = __builtin_fmaf(h, wq[r & 3], pp);
        }
        if ((r & 1) == 0) {
            he = h;
        } else {
            unsigned d;  // low16 = bf16_rne(he) [even], high16 = bf16_rne(h) [odd]
            asm("v_cvt_pk_bf16_f32 %0, %1, %2" : "=v"(d) : "v"(he), "v"(h));
            const int q = r >> 1;      // compile-time after unroll
            if (q < 4) B0[q] = d;
            else       B1[q - 4] = d;
        }
    }
    return pp;
}

// (256,4): LDS ~21 KB, arch ~60 + 64 acc VGPR -> 16 waves/CU, grid = 4
// blocks/CU exactly. Serial-issue model (R0-R8, 4x confirmed): dur == total
// occupancy cycles. Ledger at R8 (2602 cyc/wave-step): trans 1410, plain
// VALU ~550, MFMA 417, ds ~144. R9 shaves ~120 plain-VALU/ds cycles; the
// remaining slack over the additive floor (~2400) is ~3% — trans-bound.
__global__ __launch_bounds__(256, 4) void lstm_feedback_mfma22(
    const float* __restrict__ inputs,  // [B, 48]
    const float* __restrict__ Wk_w, const float* __restrict__ Uk_w, const float* __restrict__ b_w,
    const float* __restrict__ Wk_d, const float* __restrict__ Uk_d, const float* __restrict__ b_d,
    const float* __restrict__ Wd, const float* __restrict__ bd,
    float* __restrict__ out,           // [B, 24]
    int B) {
    const int tid = threadIdx.x;       // 4 waves x 32 batch = 128 batch/block
    const int w = tid >> 6;
    const int lane = tid & 63;
    const int m = lane & 31;           // batch column within wave / out-unit row
    const int H = lane >> 5;
    const int mblk = blockIdx.x * 128;
    const long row = (long)(mblk + w * 32 + m);

    __shared__ __align__(16) short uflds[16 * 64 * 8];  // 16 KB: both cells' hi U-frags
    __shared__ __align__(16) short a4lds[4 * 64 * 8];   // 4 KB: ONE cell's A4
    __shared__ float wdlds[2][16];                      // Wd in D-reg order

    // Waves 0/1 stage cell 0/1: hi U-frags (pre-scaled, permuted, RNE).
    if (w < 2) {
        const float* Uks = w ? Uk_d : Uk_w;
#pragma unroll
        for (int g = 0; g < 4; ++g) {
            const float s = gate_scale(g);
#pragma unroll
            for (int c = 0; c < 2; ++c) {
                bf16x8 ah;
#pragma unroll
                for (int j = 0; j < 8; ++j) {
                    const int uin = 16 * c + 4 * H + (j & 3) + 8 * (j >> 2);
                    float wt = Uks[uin * 128 + g * 32 + m] * s;
                    short hb, lb; bf_split_rne(wt, hb, lb);
                    ah[j] = hb;
                }
                *(bf16x8*)(uflds + (uslot(w, g, c) * 64 + lane) * 8) = ah;
            }
        }
    }
    // Warmup cell's A4 (wave 0 covers all 64 lanes x 4 gates).
    if (w == 0) stage_a4(a4lds, Wk_w, b_w, m, H, lane);
    // Wd in D-layout order: unit of D reg r is (r&3) + 8*(r>>2) + 4H.
    if (tid < 32) {
        const int r = tid & 15, Hh = tid >> 4;
        wdlds[Hh][r] = Wd[(r & 3) + 8 * (r >> 2) + 4 * Hh];
    }

    const unsigned hmask = (H == 0) ? 0xFFFFFFFFu : 0u;

    u32x4 z4 = {0u, 0u, 0u, 0u};
    u32x4 B0 = z4, B1 = z4;
    float cs[16];
#pragma unroll
    for (int r = 0; r < 16; ++r) cs[r] = 0.0f;

    __syncthreads();  // uflds + a4lds + wdlds visible

    const short* __restrict__ uf_w = uflds;
    const short* __restrict__ uf_d = uflds + 8 * 64 * 8;
    const float* __restrict__ wdp = &wdlds[H][0];

    // ---- warmup: per-lane x from global (L2-resident), one-step prefetch ----
    float xc = inputs[row * TSTEPS + 0];
    for (int t = 0; t < TSTEPS - 1; ++t) {
        float xn = inputs[row * TSTEPS + t + 1];  // issued before the step body
        asm volatile("" ::: "memory");  // keep LDS frag reads in-loop (anti-LICM)
        lstm_step32<false>(xc, uf_w, a4lds, B0, B1, cs, wdp, lane, hmask);
        xc = xn;
    }

    const float bdv = bd[0];

    // ---- last warmup step with pred fold; single-shuffle reduce ----
    asm volatile("" ::: "memory");
    float p = lstm_step32<true>(xc, uf_w, a4lds, B0, B1, cs, wdp, lane, hmask);
    p += __shfl_xor(p, 32);
    p += bdv;                          // both H lanes of batch m hold pred(batch m)
    if (H == 0) out[row * OUT_STEPS + 0] = p;

    // ---- transition: restage A4 for the decode cell (once, off hot path) ----
    __syncthreads();                   // all waves done reading warmup A4
    if (w == 0) stage_a4(a4lds, Wk_d, b_d, m, H, lane);
    __syncthreads();                   // decode A4 visible

    // ---- decode: U pointer swap; A4 already swapped in LDS ----
    for (int s = 1; s < OUT_STEPS; ++s) {
        asm volatile("" ::: "memory");
        p = lstm_step32<true>(p, uf_d, a4lds, B0, B1, cs, wdp, lane, hmask);
        p += __shfl_xor(p, 32);
        p += bdv;
        if (H == 0) out[row * OUT_STEPS + s] = p;
    }
}

extern "C" void kernel_launch(void* const* d_in, const int* in_sizes, int n_in,
                              void* d_out, int out_size, void* d_ws, size_t ws_size,
                              hipStream_t stream) {
    const float* inputs = (const float*)d_in[0];
    const float* Wk_w   = (const float*)d_in[1];
    const float* Uk_w   = (const float*)d_in[2];
    const float* b_w    = (const float*)d_in[3];
    const float* Wk_d   = (const float*)d_in[4];
    const float* Uk_d   = (const float*)d_in[5];
    const float* b_d    = (const float*)d_in[6];
    const float* Wd     = (const float*)d_in[7];
    const float* bd     = (const float*)d_in[8];
    float* out = (float*)d_out;

    const int B = in_sizes[0] / TSTEPS;
    const int grid = (B + 127) / 128;  // 128 batch rows per 256-thread block
    lstm_feedback_mfma22<<<grid, 256, 0, stream>>>(
        inputs, Wk_w, Uk_w, b_w, Wk_d, Uk_d, b_d, Wd, bd, out, B);
}

// Round 10
// 311.662 us; speedup vs baseline: 1.4706x; 1.0209x over previous
//
#include <hip/hip_runtime.h>

#define TSTEPS 48
#define OUT_STEPS 24
#define L2E 1.44269504088896340736f
#define ECLAMP 30.0f

typedef short bf16x8 __attribute__((ext_vector_type(8)));
typedef float f32x16 __attribute__((ext_vector_type(16)));
typedef float f32x4 __attribute__((ext_vector_type(4)));
typedef unsigned int u32x4 __attribute__((ext_vector_type(4)));

// RNE bf16 hi + truncated-residual lo (weights; off hot path).
__device__ __forceinline__ void bf_split_rne(float f, short& hi, short& lo) {
    unsigned u = __builtin_bit_cast(unsigned, f);
    unsigned r = u + 0x7FFFu + ((u >> 16) & 1u);
    unsigned short hb = (unsigned short)(r >> 16);
    float hif = __builtin_bit_cast(float, (unsigned)hb << 16);
    float lof = f - hif;
    unsigned short lb = (unsigned short)(__builtin_bit_cast(unsigned, lof) >> 16);
    hi = (short)hb; lo = (short)lb;
}

// Gate pre-scale for exp2: i,f,o -> -log2e; g (gate 2) -> -2*log2e.
__device__ __forceinline__ float gate_scale(int g) {
    return (g == 2) ? (-2.0f * L2E) : (-L2E);
}

// U-frag LDS slot (hi-only): (cell*4+g)*2+c, addr (slot*64+lane)*16B.
__device__ __forceinline__ int uslot(int cell, int g, int c) {
    return (cell * 4 + g) * 2 + c;
}

// Per-lane A4 frags IN REGISTERS (R10: no LDS roundtrip, no barriers).
// Layout (R9-verified): [wk_hi, wk_lo, b_hi, b_lo, 0,0,0,0], B4 = [x,x,1,1].
__device__ __forceinline__ void make_a4(const float* __restrict__ Wks,
                                        const float* __restrict__ bvs,
                                        int m, int H, bf16x8* a4) {
#pragma unroll
    for (int g = 0; g < 4; ++g) {
        const float s = gate_scale(g);
        short whi, wlo, bhi, blo;
        bf_split_rne(Wks[g * 32 + m] * s, whi, wlo);
        bf_split_rne(bvs[g * 32 + m] * s, bhi, blo);
        bf16x8 a = {whi, wlo, bhi, blo, 0, 0, 0, 0};
        u32x4 z4 = {0u, 0u, 0u, 0u};
        if (H != 0) a = __builtin_bit_cast(bf16x8, z4);
        a4[g] = a;
    }
}

// One LSTM step for 32 batch rows. Activation body VERBATIM from R9
// (verified 283us / 4.88e-4). R10 delta: ALL operands (U-frags, A4, Wd)
// are register-resident — zero LDS/global traffic in the step. 12 MFMA:
// per gate A4*B4, Ah0*B0, Ah1*B1; h carried as RNE bf16 via cvt_pk.
template <bool NEED_P>
__device__ __forceinline__ float lstm_step32(float x,
    const bf16x8* __restrict__ uf0,   // [4] K-half 0 U-frags (regs)
    const bf16x8* __restrict__ uf1,   // [4] K-half 1 U-frags (regs)
    const bf16x8* __restrict__ a4,    // [4] Wk/b frags (regs)
    u32x4& B0, u32x4& B1,
    float* cs, const f32x4* __restrict__ wq,  // [4] Wd in D-reg order (regs)
    unsigned hmask) {
    // B4 on H==0 lanes: [x_rne, x_rne, 1, 1, 0,0,0,0].
    unsigned xr;
    asm("v_cvt_pk_bf16_f32 %0, %1, %2" : "=v"(xr) : "v"(x), "v"(x));
    unsigned w0 = xr & hmask;
    unsigned w1 = 0x3F803F80u & hmask;
    u32x4 b4u = {w0, w1, 0u, 0u};
    const bf16x8 B4 = __builtin_bit_cast(bf16x8, b4u);
    const bf16x8 b0 = __builtin_bit_cast(bf16x8, B0);
    const bf16x8 b1 = __builtin_bit_cast(bf16x8, B1);
    const f32x16 zero16 = {0,0,0,0,0,0,0,0,0,0,0,0,0,0,0,0};

    f32x16 acc[4];
#pragma unroll
    for (int g = 0; g < 4; ++g) {
        f32x16 a = __builtin_amdgcn_mfma_f32_32x32x16_bf16(a4[g], B4, zero16, 0, 0, 0);
        a = __builtin_amdgcn_mfma_f32_32x32x16_bf16(uf0[g], b0, a, 0, 0, 0);
        a = __builtin_amdgcn_mfma_f32_32x32x16_bf16(uf1[g], b1, a, 0, 0, 0);
        acc[g] = a;
    }

    float pp = 0.0f;
    float he = 0.0f;                   // even-row h, packed on the odd row
#pragma unroll
    for (int r = 0; r < 16; ++r) {
        float ei = __builtin_amdgcn_exp2f(acc[0][r]);
        float ef = __builtin_amdgcn_exp2f(acc[1][r]);
        float eg = __builtin_amdgcn_exp2f(acc[2][r]);             // fmin dropped (R9)
        float eo = __builtin_amdgcn_exp2f(acc[3][r]);
        float di = 1.0f + ei, df = 1.0f + ef, dg = 1.0f + eg, do_ = 1.0f + eo;
        float ngs = __builtin_fmaf(eg, 2.0f * L2E, -2.0f * L2E);  // -2L2E*(1-eg)
        float t1 = di * dg;
        float t2 = cs[r] * t1;
        float num = __builtin_fmaf(ngs, df, t2);
        float cn = num * __builtin_amdgcn_rcpf(df * t1);          // scaled c'
        cs[r] = cn;
        float ec = __builtin_amdgcn_exp2f(__builtin_fminf(cn, ECLAMP)); // e^-2c
        float den = __builtin_fmaf(ec, do_, do_);                 // do*(1+ec)
        float inv = __builtin_amdgcn_rcpf(den);
        float h = __builtin_fmaf(-ec, inv, inv);                  // (1-ec)*inv
        if constexpr (NEED_P) pp = __builtin_fmaf(h, wq[r >> 2][r & 3], pp);
        if ((r & 1) == 0) {
            he = h;
        } else {
            unsigned d;  // low16 = bf16_rne(he) [even], high16 = bf16_rne(h) [odd]
            asm("v_cvt_pk_bf16_f32 %0, %1, %2" : "=v"(d) : "v"(he), "v"(h));
            const int q = r >> 1;      // compile-time after unroll
            if (q < 4) B0[q] = d;
            else       B1[q - 4] = d;
        }
    }
    return pp;
}

// (256,2): R10 inverts the R2 LDS decision. Serial-issue model (5x
// confirmed R0-R9): dur == total instruction-occupancy cycles; occupancy
// beyond latency-hiding is irrelevant (R0-R3 invariance). So trade
// occupancy (16->8 waves/CU) for zero per-step LDS issue: U-frags/A4/Wd
// hoisted to ~173 arch VGPRs (cap 256 at 2 waves/SIMD -> no spills, the
// R1 failure mode). 2 blocks/CU x 512 co-resident = exactly 2 clean
// rounds of the 1024-block grid. Ledger: 2393 - ~160 ds/addr -> ~2230
// cyc/wave-step. The residual floor is trans 1410 (63%) — algebraic
// minimum of 5 exp2 + 2 rcp per cell.
__global__ __launch_bounds__(256, 2) void lstm_feedback_mfma23(
    const float* __restrict__ inputs,  // [B, 48]
    const float* __restrict__ Wk_w, const float* __restrict__ Uk_w, const float* __restrict__ b_w,
    const float* __restrict__ Wk_d, const float* __restrict__ Uk_d, const float* __restrict__ b_d,
    const float* __restrict__ Wd, const float* __restrict__ bd,
    float* __restrict__ out,           // [B, 24]
    int B) {
    const int tid = threadIdx.x;       // 4 waves x 32 batch = 128 batch/block
    const int w = tid >> 6;
    const int lane = tid & 63;
    const int m = lane & 31;           // batch column within wave / out-unit row
    const int H = lane >> 5;
    const int mblk = blockIdx.x * 128;
    const long row = (long)(mblk + w * 32 + m);

    __shared__ __align__(16) short uflds[16 * 64 * 8];  // 16 KB: both cells' hi U-frags

    // Waves 0/1 stage cell 0/1: hi U-frags (pre-scaled, permuted, RNE).
    if (w < 2) {
        const float* Uks = w ? Uk_d : Uk_w;
#pragma unroll
        for (int g = 0; g < 4; ++g) {
            const float s = gate_scale(g);
#pragma unroll
            for (int c = 0; c < 2; ++c) {
                bf16x8 ah;
#pragma unroll
                for (int j = 0; j < 8; ++j) {
                    const int uin = 16 * c + 4 * H + (j & 3) + 8 * (j >> 2);
                    float wt = Uks[uin * 128 + g * 32 + m] * s;
                    short hb, lb; bf_split_rne(wt, hb, lb);
                    ah[j] = hb;
                }
                *(bf16x8*)(uflds + (uslot(w, g, c) * 64 + lane) * 8) = ah;
            }
        }
    }

    const unsigned hmask = (H == 0) ? 0xFFFFFFFFu : 0u;

    // Wd in D-layout order, straight from global (L2-broadcast, one-time).
    f32x4 wq[4];
#pragma unroll
    for (int r = 0; r < 16; ++r)
        wq[r >> 2][r & 3] = Wd[(r & 3) + 8 * (r >> 2) + 4 * H];

    // Warmup cell's A4 in registers.
    bf16x8 a4[4];
    make_a4(Wk_w, b_w, m, H, a4);

    u32x4 z4 = {0u, 0u, 0u, 0u};
    u32x4 B0 = z4, B1 = z4;
    float cs[16];
#pragma unroll
    for (int r = 0; r < 16; ++r) cs[r] = 0.0f;

    __syncthreads();  // uflds visible

    // Hoist warmup-cell U-frags into registers (one-time; 8 ds_read_b128).
    bf16x8 uf0[4], uf1[4];
#pragma unroll
    for (int g = 0; g < 4; ++g) {
        uf0[g] = *(const bf16x8*)(uflds + (uslot(0, g, 0) * 64 + lane) * 8);
        uf1[g] = *(const bf16x8*)(uflds + (uslot(0, g, 1) * 64 + lane) * 8);
    }

    // ---- warmup: per-lane x from global (L2-resident), one-step prefetch ----
    float xc = inputs[row * TSTEPS + 0];
    for (int t = 0; t < TSTEPS - 1; ++t) {
        float xn = inputs[row * TSTEPS + t + 1];  // issued before the step body
        lstm_step32<false>(xc, uf0, uf1, a4, B0, B1, cs, wq, hmask);
        xc = xn;
    }

    const float bdv = bd[0];

    // ---- last warmup step with pred fold; single-shuffle reduce ----
    float p = lstm_step32<true>(xc, uf0, uf1, a4, B0, B1, cs, wq, hmask);
    p += __shfl_xor(p, 32);
    p += bdv;                          // both H lanes of batch m hold pred(batch m)
    if (H == 0) out[row * OUT_STEPS + 0] = p;

    // ---- transition: decode-cell operands into the same registers ----
    make_a4(Wk_d, b_d, m, H, a4);      // per-lane, global L2 (no barrier needed)
#pragma unroll
    for (int g = 0; g < 4; ++g) {      // uflds unchanged since staging barrier
        uf0[g] = *(const bf16x8*)(uflds + (uslot(1, g, 0) * 64 + lane) * 8);
        uf1[g] = *(const bf16x8*)(uflds + (uslot(1, g, 1) * 64 + lane) * 8);
    }

    // ---- decode ----
    for (int s = 1; s < OUT_STEPS; ++s) {
        p = lstm_step32<true>(p, uf0, uf1, a4, B0, B1, cs, wq, hmask);
        p += __shfl_xor(p, 32);
        p += bdv;
        if (H == 0) out[row * OUT_STEPS + s] = p;
    }
}

extern "C" void kernel_launch(void* const* d_in, const int* in_sizes, int n_in,
                              void* d_out, int out_size, void* d_ws, size_t ws_size,
                              hipStream_t stream) {
    const float* inputs = (const float*)d_in[0];
    const float* Wk_w   = (const float*)d_in[1];
    const float* Uk_w   = (const float*)d_in[2];
    const float* b_w    = (const float*)d_in[3];
    const float* Wk_d   = (const float*)d_in[4];
    const float* Uk_d   = (const float*)d_in[5];
    const float* b_d    = (const float*)d_in[6];
    const float* Wd     = (const float*)d_in[7];
    const float* bd     = (const float*)d_in[8];
    float* out = (float*)d_out;

    const int B = in_sizes[0] / TSTEPS;
    const int grid = (B + 127) / 128;  // 128 batch rows per 256-thread block
    lstm_feedback_mfma23<<<grid, 256, 0, stream>>>(
        inputs, Wk_w, Uk_w, b_w, Wk_d, Uk_d, b_d, Wd, bd, out, B);
}